// Round 4
// baseline (192.143 us; speedup 1.0000x reference)
//
#include <hip/hip_runtime.h>
#include <hip/hip_fp16.h>
#include <stdint.h>

// Problem constants (fixed by the reference):
#define MQ 8192   // N*C queries
#define NK 1024   // K codewords
#define DD 1024   // H*W
#define SCALE_LO 2048.0f         // 2^11: lift f16 lo-parts out of subnormal range
#define INV_LO   (1.0f / 2048.0f)

typedef _Float16 half8_t __attribute__((ext_vector_type(8)));
typedef _Float16 half4_t __attribute__((ext_vector_type(4)));
typedef float    floatx4 __attribute__((ext_vector_type(4)));

// async global->LDS, 16B per lane; LDS dest is wave-uniform base + lane*16
#define GLOAD_LDS16(gp, lp)                                                   \
  __builtin_amdgcn_global_load_lds(                                           \
      (const __attribute__((address_space(1))) void*)(gp),                    \
      (__attribute__((address_space(3))) void*)(lp), 16, 0, 0)

// ---------- fused prep: split x, split codebook (+norms), init keys ----------
__global__ void k_prep(const float* __restrict__ x, const float* __restrict__ cb,
                       _Float16* __restrict__ ah, _Float16* __restrict__ al,
                       _Float16* __restrict__ bh, _Float16* __restrict__ bl,
                       float* __restrict__ csqr,
                       unsigned long long* __restrict__ keys) {
  const int bid = blockIdx.x;
  const int t = threadIdx.x;
  if (bid < 8192) {
    int i = bid * 256 + t;
    float4 v = ((const float4*)x)[i];
    float vv[4] = {v.x, v.y, v.z, v.w};
    half4_t h, l;
#pragma unroll
    for (int j = 0; j < 4; ++j) {
      _Float16 hh = (_Float16)vv[j];
      h[j] = hh;
      l[j] = (_Float16)((vv[j] - (float)hh) * SCALE_LO);  // (v-h) exact in fp32
    }
    ((half4_t*)ah)[i] = h;
    ((half4_t*)al)[i] = l;
  } else {
    int k = bid - 8192;
    if (k < 32) keys[k * 256 + t] = ~0ULL;
    float4 v = ((const float4*)(cb + (size_t)k * DD))[t];
    float vv[4] = {v.x, v.y, v.z, v.w};
    half4_t h, l;
    double s = 0.0;
#pragma unroll
    for (int j = 0; j < 4; ++j) {
      _Float16 hh = (_Float16)vv[j];
      h[j] = hh;
      l[j] = (_Float16)((vv[j] - (float)hh) * SCALE_LO);
      s += (double)vv[j] * (double)vv[j];
    }
    ((half4_t*)(bh + (size_t)k * DD))[t] = h;
    ((half4_t*)(bl + (size_t)k * DD))[t] = l;
    for (int m = 32; m >= 1; m >>= 1) s += __shfl_xor(s, m, 64);
    __shared__ double red[4];
    if ((t & 63) == 0) red[t >> 6] = s;
    __syncthreads();
    if (t == 0) csqr[k] = (float)(red[0] + red[1] + red[2] + red[3] - 1024.0);
  }
}

__device__ __forceinline__ unsigned sortable_u32(float f) {
  unsigned u = __float_as_uint(f);
  return (u & 0x80000000u) ? ~u : (u | 0x80000000u);
}

// ------------- fused f16x3 GEMM (M=8192,N=1024,Kvirt=3072) + argmin -------------
// Tile 64(M)x128(N), grid 8x128 = 1024 blocks = 4 blocks/CU (R3 was 512 = 2/CU,
// occupancy-starved at 20%). Each wave: full M=64 x N-slice 32 -> 4x2 MFMA tiles.
// seg0: Ah*Bl' , seg1: Al'*Bh  (both scaled 2^11)  -> acc *= 2^-11 -> seg2: Ah*Bh
__global__ __launch_bounds__(256) void k_gemm_argmin(
    const _Float16* __restrict__ Ah, const _Float16* __restrict__ Al,
    const _Float16* __restrict__ Bh, const _Float16* __restrict__ Bl,
    const float* __restrict__ csqr, unsigned long long* __restrict__ keys) {
  __shared__ _Float16 sA[64 * 32];   // 4 KB, row-major [row][32], unpadded
  __shared__ _Float16 sB[128 * 32];  // 8 KB (global_load_lds forbids padding)

  const int tid = threadIdx.x;
  const int bn = blockIdx.x;          // 0..7    (N tiles of 128)
  const int bm = blockIdx.y;          // 0..127  (M tiles of 64)
  const int m0 = bm * 64, n0 = bn * 128;
  const int wave = tid >> 6, lane = tid & 63;
  const int quad = lane >> 4, l15 = lane & 15;

  floatx4 acc[4][2];
#pragma unroll
  for (int i = 0; i < 4; ++i)
#pragma unroll
    for (int j = 0; j < 2; ++j) acc[i][j] = (floatx4){0.f, 0.f, 0.f, 0.f};

  // staging: chunk t = 16B at LDS linear t*16; row = t>>2, k-off = (t&3)*8
  const int r0 = tid >> 2;
  const int c0 = (tid & 3) * 8;
  _Float16* sAw = sA + wave * 512;           // wave-uniform LDS bases (halfs)
  _Float16* sBw = sB + wave * 512;
  _Float16* sBw2 = sB + 2048 + wave * 512;

  for (int kb = 0; kb < 96; ++kb) {
    const int seg = kb >> 5;
    const _Float16* Ap = (seg == 1) ? Al : Ah;
    const _Float16* Bp = (seg == 0) ? Bl : Bh;
    const int kk = (kb & 31) * 32;

    if (kb == 64) {  // rescale the 2^11-scaled lo-segments before hi*hi accumulates
#pragma unroll
      for (int i = 0; i < 4; ++i)
#pragma unroll
        for (int j = 0; j < 2; ++j) acc[i][j] *= INV_LO;
    }

    __syncthreads();  // prior iteration's fragment reads done
    GLOAD_LDS16(Ap + (size_t)(m0 + r0) * DD + kk + c0, sAw);
    GLOAD_LDS16(Bp + (size_t)(n0 + r0) * DD + kk + c0, sBw);
    GLOAD_LDS16(Bp + (size_t)(n0 + 64 + r0) * DD + kk + c0, sBw2);
    __syncthreads();  // drains vmcnt -> LDS tile complete

    half8_t af[4], bf[2];
#pragma unroll
    for (int i = 0; i < 4; ++i)
      af[i] = *(const half8_t*)(sA + (i * 16 + l15) * 32 + quad * 8);
#pragma unroll
    for (int j = 0; j < 2; ++j)
      bf[j] = *(const half8_t*)(sB + (wave * 32 + j * 16 + l15) * 32 + quad * 8);
#pragma unroll
    for (int i = 0; i < 4; ++i)
#pragma unroll
      for (int j = 0; j < 2; ++j)
        acc[i][j] = __builtin_amdgcn_mfma_f32_16x16x32_f16(af[i], bf[j], acc[i][j], 0, 0, 0);
  }

  // epilogue: score = csqr[n] - 2*dot ; pack (sortable_score, n) ; per-row argmin
  float csv[2];
#pragma unroll
  for (int j = 0; j < 2; ++j) csv[j] = csqr[n0 + wave * 32 + j * 16 + l15];

#pragma unroll
  for (int i = 0; i < 4; ++i) {
#pragma unroll
    for (int r = 0; r < 4; ++r) {
      const int row = m0 + i * 16 + quad * 4 + r;  // C/D: col=lane&15, row=quad*4+reg
      unsigned long long best = ~0ULL;
#pragma unroll
      for (int j = 0; j < 2; ++j) {
        float s = csv[j] - 2.0f * acc[i][j][r];
        unsigned long long key = ((unsigned long long)sortable_u32(s) << 32) |
                                 (unsigned)(n0 + wave * 32 + j * 16 + l15);
        best = key < best ? key : best;
      }
#pragma unroll
      for (int m = 1; m <= 8; m <<= 1) {  // reduce over the 16 cols held by this quad-group
        unsigned long long o = __shfl_xor(best, m, 64);
        best = o < best ? o : best;
      }
      if (l15 == 0) atomicMin(&keys[row], best);
    }
  }
}

// ---------------- gather winning codeword, write both tuple outputs ----------------
// Overwrites ALL of d_out (including the regions used as f16 scratch earlier).
__global__ void k_gather(const unsigned long long* __restrict__ keys,
                         const float* __restrict__ cb, float* __restrict__ out) {
  int m = blockIdx.x;
  int idx = (int)(keys[m] & 0xFFFFFFFFULL);
  float4 v = ((const float4*)(cb + (size_t)idx * DD))[threadIdx.x];
  ((float4*)(out + (size_t)m * DD))[threadIdx.x] = v;
  ((float4*)(out + (size_t)(m + MQ) * DD))[threadIdx.x] = v;
}

extern "C" void kernel_launch(void* const* d_in, const int* in_sizes, int n_in,
                              void* d_out, int out_size, void* d_ws, size_t ws_size,
                              hipStream_t stream) {
  const float* x = (const float*)d_in[0];
  const float* cb = (const float*)d_in[1];
  float* out = (float*)d_out;

  // Big f16 scratch lives inside d_out (64 MB, fully overwritten by k_gather at
  // the end). d_ws only holds 68 KB (csqr + keys) — R1's d_ws overflow corrupted
  // the harness's pristine inputs; never assume ws_size.
  char* ob = (char*)d_out;
  _Float16* Ah = (_Float16*)(ob);                                   // 16 MB
  _Float16* Al = (_Float16*)(ob + (size_t)16 * 1024 * 1024);        // 16 MB
  _Float16* Bh = (_Float16*)(ob + (size_t)32 * 1024 * 1024);        // 2 MB
  _Float16* Bl = (_Float16*)(ob + (size_t)34 * 1024 * 1024);        // 2 MB

  char* ws = (char*)d_ws;
  float* csqr = (float*)(ws);                                       // 4 KB
  unsigned long long* keys = (unsigned long long*)(ws + 4096);      // 64 KB

  k_prep<<<8192 + 1024, 256, 0, stream>>>(x, cb, Ah, Al, Bh, Bl, csqr, keys);
  k_gemm_argmin<<<dim3(8, 128), 256, 0, stream>>>(Ah, Al, Bh, Bl, csqr, keys);
  k_gather<<<MQ, 256, 0, stream>>>(keys, cb, out);
}

// Round 5
// 136.573 us; speedup vs baseline: 1.4069x; 1.4069x over previous
//
#include <hip/hip_runtime.h>
#include <hip/hip_fp16.h>
#include <stdint.h>

// Problem constants (fixed by the reference):
#define MQ 8192   // N*C queries
#define NK 1024   // K codewords
#define DD 1024   // H*W
#define DELTA 2.0f  // screen slack: covers 2*(f16 score quant 0.5 + 5sigma arith 0.13)

typedef _Float16 half8_t __attribute__((ext_vector_type(8)));
typedef _Float16 half4_t __attribute__((ext_vector_type(4)));
typedef float    floatx4 __attribute__((ext_vector_type(4)));

// async global->LDS, 16B per lane; LDS dest is wave-uniform base + lane*16
#define GLOAD_LDS16(gp, lp)                                                   \
  __builtin_amdgcn_global_load_lds(                                           \
      (const __attribute__((address_space(1))) void*)(gp),                    \
      (__attribute__((address_space(3))) void*)(lp), 16, 0, 0)

// ---------- prep: f16 hi-parts only (screen needs no lo split) + csqr ----------
__global__ void k_prep(const float* __restrict__ x, const float* __restrict__ cb,
                       _Float16* __restrict__ ah, _Float16* __restrict__ bh,
                       float* __restrict__ csqr) {
  const int bid = blockIdx.x;
  const int t = threadIdx.x;
  if (bid < 8192) {
    int i = bid * 256 + t;
    float4 v = ((const float4*)x)[i];
    float vv[4] = {v.x, v.y, v.z, v.w};
    half4_t h;
#pragma unroll
    for (int j = 0; j < 4; ++j) h[j] = (_Float16)vv[j];
    ((half4_t*)ah)[i] = h;
  } else {
    int k = bid - 8192;
    float4 v = ((const float4*)(cb + (size_t)k * DD))[t];
    float vv[4] = {v.x, v.y, v.z, v.w};
    half4_t h;
    double s = 0.0;
#pragma unroll
    for (int j = 0; j < 4; ++j) {
      h[j] = (_Float16)vv[j];
      s += (double)vv[j] * (double)vv[j];
    }
    ((half4_t*)(bh + (size_t)k * DD))[t] = h;
    for (int m = 32; m >= 1; m >>= 1) s += __shfl_xor(s, m, 64);
    __shared__ double red[4];
    if ((t & 63) == 0) red[t >> 6] = s;
    __syncthreads();
    if (t == 0) csqr[k] = (float)(red[0] + red[1] + red[2] + red[3] - 1024.0);
  }
}

__device__ __forceinline__ unsigned sortable_u32(float f) {
  unsigned u = __float_as_uint(f);
  return (u & 0x80000000u) ? ~u : (u | 0x80000000u);
}

// ---------------- phase A: hi*hi screen GEMM, stores f16 score matrix ----------------
// S[m][n] = f16(csqr[n] - 2 * dot(xh[m], ch[n])) ; 128x128 tile (R3-proven layout)
__global__ __launch_bounds__(256) void k_screen(
    const _Float16* __restrict__ Ah, const _Float16* __restrict__ Bh,
    const float* __restrict__ csqr, _Float16* __restrict__ S) {
  __shared__ _Float16 sA[128 * 32];  // row-major [row][32], unpadded
  __shared__ _Float16 sB[128 * 32];  // (global_load_lds forbids padding)

  const int tid = threadIdx.x;
  const int bn = blockIdx.x;          // 0..7   (N tiles)
  const int bm = blockIdx.y;          // 0..63  (M tiles)
  const int m0 = bm * 128, n0 = bn * 128;
  const int wave = tid >> 6, lane = tid & 63;
  const int wm = wave & 1, wn = wave >> 1;
  const int quad = lane >> 4, l15 = lane & 15;

  floatx4 acc[4][4];
#pragma unroll
  for (int i = 0; i < 4; ++i)
#pragma unroll
    for (int j = 0; j < 4; ++j) acc[i][j] = (floatx4){0.f, 0.f, 0.f, 0.f};

  const int r0 = tid >> 2;
  const int c0 = (tid & 3) * 8;
  _Float16* sAw = sA + wave * 512;
  _Float16* sAw2 = sA + 2048 + wave * 512;
  _Float16* sBw = sB + wave * 512;
  _Float16* sBw2 = sB + 2048 + wave * 512;

  for (int kb = 0; kb < 32; ++kb) {  // K=1024 only (hi*hi segment)
    const int kk = kb * 32;
    __syncthreads();
    GLOAD_LDS16(Ah + (size_t)(m0 + r0) * DD + kk + c0, sAw);
    GLOAD_LDS16(Ah + (size_t)(m0 + 64 + r0) * DD + kk + c0, sAw2);
    GLOAD_LDS16(Bh + (size_t)(n0 + r0) * DD + kk + c0, sBw);
    GLOAD_LDS16(Bh + (size_t)(n0 + 64 + r0) * DD + kk + c0, sBw2);
    __syncthreads();

    half8_t af[4], bf[4];
#pragma unroll
    for (int i = 0; i < 4; ++i)
      af[i] = *(const half8_t*)(sA + (wm * 64 + i * 16 + l15) * 32 + quad * 8);
#pragma unroll
    for (int j = 0; j < 4; ++j)
      bf[j] = *(const half8_t*)(sB + (wn * 64 + j * 16 + l15) * 32 + quad * 8);
#pragma unroll
    for (int i = 0; i < 4; ++i)
#pragma unroll
      for (int j = 0; j < 4; ++j)
        acc[i][j] = __builtin_amdgcn_mfma_f32_16x16x32_f16(af[i], bf[j], acc[i][j], 0, 0, 0);
  }

  // epilogue: write f16 approx scores (no atomics, no keys)
  float csv[4];
#pragma unroll
  for (int j = 0; j < 4; ++j) csv[j] = csqr[n0 + wn * 64 + j * 16 + l15];
#pragma unroll
  for (int i = 0; i < 4; ++i)
#pragma unroll
    for (int r = 0; r < 4; ++r) {
      const int row = m0 + wm * 64 + i * 16 + quad * 4 + r;  // C/D: col=lane&15, row=quad*4+reg
#pragma unroll
      for (int j = 0; j < 4; ++j) {
        const int col = n0 + wn * 64 + j * 16 + l15;
        S[(size_t)row * NK + col] = (_Float16)(csv[j] - 2.0f * acc[i][j][r]);
      }
    }
}

// -------- phase B: wave-per-row scan + exact fp32 refine + gather/write --------
__global__ __launch_bounds__(256) void k_refine(
    const _Float16* __restrict__ S, const float* __restrict__ x,
    const float* __restrict__ cb, float* __restrict__ out, int both) {
  const int wave = threadIdx.x >> 6, lane = threadIdx.x & 63;
  const int m = blockIdx.x * 4 + wave;

  // scan score row: 16 f16 per lane
  const half8_t* Srow = (const half8_t*)(S + (size_t)m * NK);
  half8_t s0 = Srow[lane * 2];
  half8_t s1 = Srow[lane * 2 + 1];
  float sc[16];
#pragma unroll
  for (int k = 0; k < 8; ++k) { sc[k] = (float)s0[k]; sc[8 + k] = (float)s1[k]; }
  float mn = sc[0];
#pragma unroll
  for (int k = 1; k < 16; ++k) mn = fminf(mn, sc[k]);
  for (int o = 1; o <= 32; o <<= 1) mn = fminf(mn, __shfl_xor(mn, o, 64));
  const float thr = mn + DELTA;

  // collect candidate indices (wave-uniform list in registers)
  int cand[12];
  int nc = 0;
#pragma unroll
  for (int s = 0; s < 16; ++s) {
    unsigned long long msk = __ballot(sc[s] <= thr);
    while (msk && nc < 12) {
      int l = __builtin_ctzll(msk);
      msk &= msk - 1;
      cand[nc++] = l * 16 + s;  // lane l holds cols l*16 + s
    }
  }

  // x row in registers: lane covers floats [q*256 + lane*4, +4)
  const float4* xr4 = (const float4*)(x + (size_t)m * DD);
  float4 xr[4];
#pragma unroll
  for (int q = 0; q < 4; ++q) xr[q] = xr4[q * 64 + lane];

  // exact fp32 refine over candidates
  unsigned long long best = ~0ULL;
  for (int c = 0; c < nc; ++c) {
    const float4* c4 = (const float4*)(cb + (size_t)cand[c] * DD);
    float d = 0.f;
#pragma unroll
    for (int q = 0; q < 4; ++q) {
      float4 v = c4[q * 64 + lane];
      float dx = xr[q].x - v.x, dy = xr[q].y - v.y;
      float dz = xr[q].z - v.z, dw = xr[q].w - v.w;
      d += dx * dx + dy * dy + dz * dz + dw * dw;
    }
    for (int o = 1; o <= 32; o <<= 1) d += __shfl_xor(d, o, 64);
    unsigned long long key =
        ((unsigned long long)sortable_u32(d) << 32) | (unsigned)cand[c];
    best = key < best ? key : best;  // ties -> lowest index (np argmin)
  }

  // gather winner, write output(s)
  const int widx = (int)(best & 0xFFFFFFFFULL);
  const float4* w4 = (const float4*)(cb + (size_t)widx * DD);
  float4* o0 = (float4*)(out + (size_t)m * DD);
  float4* o1 = (float4*)(out + (size_t)(m + MQ) * DD);
#pragma unroll
  for (int q = 0; q < 4; ++q) {
    float4 v = w4[q * 64 + lane];
    o0[q * 64 + lane] = v;
    if (both) o1[q * 64 + lane] = v;
  }
}

// d2d copy lower output copy -> upper (only when S had to live in d_out's top)
__global__ void k_copy(const float4* __restrict__ src, float4* __restrict__ dst) {
  int i = blockIdx.x * 256 + threadIdx.x;
  dst[i] = src[i];
}

extern "C" void kernel_launch(void* const* d_in, const int* in_sizes, int n_in,
                              void* d_out, int out_size, void* d_ws, size_t ws_size,
                              hipStream_t stream) {
  const float* x = (const float*)d_in[0];
  const float* cb = (const float*)d_in[1];
  float* out = (float*)d_out;
  char* ob = (char*)d_out;

  const size_t MB = 1024 * 1024;
  // Ah/Bh scratch lives in d_out (dead before any output write).
  _Float16* Ah = (_Float16*)(ob);              // [0,16MB)
  _Float16* Bh = (_Float16*)(ob + 16 * MB);    // [16,18MB)

  // S (16MB) + csqr (4KB): prefer d_ws if it's big enough (NEVER assume — R1
  // overflow corrupted harness pristine inputs). Fallback: S in d_out[48,64MB),
  // refine then writes only the lower output copy and k_copy fills the upper.
  const bool ws_ok = ws_size >= 16 * MB + 4096;
  _Float16* S;
  float* csqr;
  if (ws_ok) {
    S = (_Float16*)d_ws;
    csqr = (float*)((char*)d_ws + 16 * MB);
  } else {
    S = (_Float16*)(ob + 48 * MB);
    csqr = (float*)(ob + 18 * MB);
  }

  k_prep<<<8192 + 1024, 256, 0, stream>>>(x, cb, Ah, Bh, csqr);
  k_screen<<<dim3(8, 64), 256, 0, stream>>>(Ah, Bh, csqr, S);
  k_refine<<<2048, 256, 0, stream>>>(S, x, cb, out, ws_ok ? 1 : 0);
  if (!ws_ok) k_copy<<<8192, 256, 0, stream>>>((const float4*)out, (float4*)(ob + 32 * MB));
}